// Round 1
// 159.009 us; speedup vs baseline: 1.0172x; 1.0172x over previous
//
#include <hip/hip_runtime.h>
#include <climits>
#include <cstdint>

namespace {
constexpr int B = 4, N = 20000, C = 21, P = 100, NC = 20; // NC = C-1
constexpr float THR  = 0.7f;
constexpr float BIGF = 1.0e9f;
constexpr float MAXR = 4.135166556742356f; // |log(16/1000)| rounded to f32
constexpr float TAU  = 0.8f;               // prune threshold (verified post-hoc)
constexpr int PCAP = 512;                  // pruned-list capacity = VPW*64
constexpr int VPW  = 8;                    // slots per lane, nms wave scan
constexpr int NMT  = 512;                  // k_nms block size
constexpr int TKN  = 2048;                 // padded topk candidate count
constexpr int TVPW = 32;                   // slots per lane, topk
constexpr int NB   = (N + 255) / 256;      // 79 k_valid blocks per image
constexpr int GPB  = 2;                    // k_valid blocks per compact block
constexpr int GB   = (NB + GPB - 1) / GPB; // 40 compact blocks per image

// ws layout (bytes)
constexpr size_t OFF_CPACK = 0;                                  // B*N*8 f32 packed cand
constexpr size_t OFF_MASK  = OFF_CPACK + (size_t)B * N * 32;     // B*N u32
constexpr size_t OFF_BCNT  = OFF_MASK  + (size_t)B * N * 4;      // B*NB i32 (+pad)
constexpr size_t OFF_VCNT  = OFF_BCNT  + 2048;                   // B i32 (+pad)
constexpr size_t OFF_OIDX  = OFF_VCNT  + 64;                     // B*NC*P i32
constexpr size_t OFF_OVAL  = OFF_OIDX  + (size_t)B * NC * P * 4; // B*NC*P i32
constexpr size_t OFF_OSC   = OFF_OVAL  + (size_t)B * NC * P * 4; // B*NC*P f32 (orig le)
constexpr size_t OFF_OBOX  = OFF_OSC   + (size_t)B * NC * P * 4; // B*NC*P f32x4
constexpr size_t OFF_SFALL = OFF_OBOX  + (size_t)B * NC * P * 16;// B*NC*N f32 fallback
} // namespace

// ---------------------------------------------------------------------------
// DPP wave64 fmax reduce (VALU-only); result broadcast via readlane 63.
// ---------------------------------------------------------------------------
template <int CTRL, int RM>
__device__ __forceinline__ float dpp_fmax(float x) {
  int t = __builtin_amdgcn_update_dpp(__float_as_int(x), __float_as_int(x),
                                      CTRL, RM, 0xF, false);
  return fmaxf(x, __int_as_float(t));
}
__device__ __forceinline__ float wave_fmax64(float x) {
  x = dpp_fmax<0x111, 0xF>(x); // row_shr:1
  x = dpp_fmax<0x112, 0xF>(x); // row_shr:2
  x = dpp_fmax<0x114, 0xF>(x); // row_shr:4
  x = dpp_fmax<0x118, 0xF>(x); // row_shr:8
  x = dpp_fmax<0x142, 0xA>(x); // row_bcast:15 -> rows 1,3
  x = dpp_fmax<0x143, 0xC>(x); // row_bcast:31 -> rows 2,3
  return __int_as_float(__builtin_amdgcn_readlane(__float_as_int(x), 63));
}
__device__ __forceinline__ int rlane_i(int x, int l) {
  return __builtin_amdgcn_readlane(x, l);
}
// fast native ops for the decay weights (selection-only values; exp2(-0)=1
// exactly so non-overlapping candidates stay bit-identical to np)
__device__ __forceinline__ float fast_rcp(float x) {
  return __builtin_amdgcn_rcpf(x);
}
__device__ __forceinline__ float fast_exp2(float x) {
  return __builtin_amdgcn_exp2f(x);
}

#define NMS_ALL(X) X(0) X(1) X(2) X(3) X(4) X(5) X(6) X(7)
#define NMS_REV(X) X(7) X(6) X(5) X(4) X(3) X(2) X(1) X(0)
#define TK_ALL(X) X(0) X(1) X(2) X(3) X(4) X(5) X(6) X(7) X(8) X(9) X(10) \
  X(11) X(12) X(13) X(14) X(15) X(16) X(17) X(18) X(19) X(20) X(21) X(22) \
  X(23) X(24) X(25) X(26) X(27) X(28) X(29) X(30) X(31)
#define TK_REV(X) X(31) X(30) X(29) X(28) X(27) X(26) X(25) X(24) X(23) \
  X(22) X(21) X(20) X(19) X(18) X(17) X(16) X(15) X(14) X(13) X(12) X(11) \
  X(10) X(9) X(8) X(7) X(6) X(5) X(4) X(3) X(2) X(1) X(0)

// ---------------------------------------------------------------------------
// Kernel 1: per-anchor le/argmax/valid + tau bitmask + per-block valid count.
// ---------------------------------------------------------------------------
__global__ __launch_bounds__(256) void k_valid(
    const float* __restrict__ score, const float* __restrict__ logits,
    unsigned* __restrict__ mask, int* __restrict__ bcnt) {
  __shared__ int ws[4];
  int tid = threadIdx.x;
  int n = blockIdx.x * 256 + tid;
  int b = blockIdx.y;
  unsigned mk = 0;
  if (n < N) {
    int bn = b * N + n;
    float sc = score[bn];
    const float* lg = logits + (size_t)bn * C;
    float le[C];
    float ms = -INFINITY;
    int lab = 0;
    #pragma unroll
    for (int c = 0; c < C; ++c) {
      le[c] = __fmul_rn(sc, lg[c]);
      if (le[c] > ms) { ms = le[c]; lab = c; }  // strict > keeps first max
    }
    if (ms >= THR && lab > 0) {
      mk = 1u << 20;
      #pragma unroll
      for (int c = 1; c < C; ++c)
        if (le[c] >= TAU) mk |= 1u << (c - 1);
    }
    mask[bn] = mk;
  }
  unsigned long long vb = __ballot(mk != 0);
  if ((tid & 63) == 0) ws[tid >> 6] = __popcll(vb);
  __syncthreads();
  if (tid == 0) bcnt[b * NB + blockIdx.x] = ws[0] + ws[1] + ws[2] + ws[3];
}

// ---------------------------------------------------------------------------
// Kernel 2: segmented stable compaction + box decode into packed 32B records
// {x1,y1,x2,y2, n(bits), score, area, mask(bits)}. Grid (GB, B), 256 thr.
// ---------------------------------------------------------------------------
__global__ __launch_bounds__(256) void k_compact(
    const float* __restrict__ score, const float* __restrict__ regress,
    const float* __restrict__ anchors, const unsigned* __restrict__ mask,
    const int* __restrict__ bcnt, float* __restrict__ cpack,
    int* __restrict__ vcnt) {
  __shared__ int s_base[4], s_tot[4], s_scan[4];
  int g = blockIdx.x, b = blockIdx.y;
  int tid = threadIdx.x, lane = tid & 63, wid = tid >> 6;
  int idx0 = g * GPB;
  int bv = (tid < idx0) ? bcnt[b * NB + tid] : 0;
  int tv = (tid < NB) ? bcnt[b * NB + tid] : 0;
  #pragma unroll
  for (int off = 32; off; off >>= 1) {
    bv += __shfl_down(bv, off);
    tv += __shfl_down(tv, off);
  }
  if (lane == 0) { s_base[wid] = bv; s_tot[wid] = tv; }
  __syncthreads();
  int base = s_base[0] + s_base[1] + s_base[2] + s_base[3];
  if (g == 0 && tid == 0) vcnt[b] = s_tot[0] + s_tot[1] + s_tot[2] + s_tot[3];

  int n0 = g * (GPB * 256) + tid * GPB;
  unsigned bits = 0; int cnt = 0;
  #pragma unroll
  for (int j = 0; j < GPB; ++j) {
    int n = n0 + j;
    if (n < N && (mask[b * N + n] & (1u << 20))) { bits |= 1u << j; cnt++; }
  }
  int inc = cnt;
  #pragma unroll
  for (int off = 1; off < 64; off <<= 1) {
    int o = __shfl_up(inc, off);
    if (lane >= off) inc += o;
  }
  if (lane == 63) s_scan[wid] = inc;
  __syncthreads();
  int woff = 0;
  for (int k = 0; k < wid; ++k) woff += s_scan[k];
  int pos = base + woff + inc - cnt;
  #pragma unroll
  for (int j = 0; j < GPB; ++j) {
    if (!((bits >> j) & 1u)) continue;
    int n = n0 + j;
    int bn = b * N + n;
    const float* an = anchors + (size_t)n * 4;
    float ax1 = an[0], ay1 = an[1], ax2 = an[2], ay2 = an[3];
    float aw = __fsub_rn(ax2, ax1), ah = __fsub_rn(ay2, ay1);
    float acx = __fadd_rn(ax1, __fmul_rn(0.5f, aw));
    float acy = __fadd_rn(ay1, __fmul_rn(0.5f, ah));
    const float* rg = regress + (size_t)bn * 4;
    float dx = rg[0], dy = rg[1];
    float dw = fminf(fmaxf(rg[2], -MAXR), MAXR);
    float dh = fminf(fmaxf(rg[3], -MAXR), MAXR);
    float cx = __fadd_rn(acx, __fmul_rn(dx, aw));
    float cy = __fadd_rn(acy, __fmul_rn(dy, ah));
    float w = __fmul_rn(aw, expf(dw));
    float h = __fmul_rn(ah, expf(dh));
    float hw = __fmul_rn(0.5f, w), hh = __fmul_rn(0.5f, h);
    float x1 = fminf(fmaxf(__fsub_rn(cx, hw), 0.f), 1.f);
    float y1 = fminf(fmaxf(__fsub_rn(cy, hh), 0.f), 1.f);
    float x2 = fminf(fmaxf(__fadd_rn(cx, hw), 0.f), 1.f);
    float y2 = fminf(fmaxf(__fadd_rn(cy, hh), 0.f), 1.f);
    float area = __fmul_rn(__fsub_rn(x2, x1), __fsub_rn(y2, y1));
    unsigned mk = mask[bn];
    float4* cp = reinterpret_cast<float4*>(cpack) + ((size_t)b * N + pos) * 2;
    cp[0] = make_float4(x1, y1, x2, y2);
    cp[1] = make_float4(__int_as_float(n), score[bn], area, __uint_as_float(mk));
    pos++;
  }
}

// ---------------------------------------------------------------------------
// Kernel 3: soft-NMS. One block per (image,class), 512 threads.
// Pruned list (cap PCAP) in LDS; wave0 runs the 100-step scan with named
// scalar state. Per-step serial section minimized: per-lane argmax slot (bk)
// is maintained incrementally inside the decay pass, so winner discovery is
// DPP-max + ballot + ONE readlane; the winner box is fetched with a single
// broadcast ds_read_b128 from LDS (no select chains, no box readlanes).
// Verified by v_99 >= TAU (which also implies every pick is valid, so the
// fast path emits ov=1 unconditionally); any failure -> full-V exact fallback.
// ---------------------------------------------------------------------------
__global__ __launch_bounds__(NMT) void k_nms(
    const float* __restrict__ logits, const float* __restrict__ cpack,
    const int* __restrict__ vcnt, float* __restrict__ sfall,
    int* __restrict__ oidx, int* __restrict__ oval,
    float* __restrict__ osc, float* __restrict__ obox) {
  __shared__ float4 s_box[PCAP];
  __shared__ float  s_ar[PCAP], s_s[PCAP];
  __shared__ int    s_n[PCAP];
  __shared__ int    s_selj[P];
  __shared__ int    s_wcnt[NMT / 64];
  __shared__ int    s_fail;
  __shared__ float  s_red[NMT / 64];
  __shared__ int    s_redi[NMT / 64];

  int blk = blockIdx.x;  // 0..B*NC-1
  int b = blk / NC;
  int cls = blk % NC + 1;
  int V = vcnt[b];
  int tid = threadIdx.x;
  int lane = tid & 63, wid = tid >> 6;
  constexpr int NW = NMT / 64;
  const float* cpf = cpack + (size_t)b * N * 8;
  int* oi = oidx + (size_t)blk * P;
  int* ov = oval + (size_t)blk * P;
  float* os = osc + (size_t)blk * P;
  float4* ob = reinterpret_cast<float4*>(obox) + (size_t)blk * P;
  unsigned clsbit = 1u << (cls - 1);

  // ---- pass 1: count candidates with le >= TAU for this class ----
  int ch = (V + NMT - 1) / NMT;
  int v0 = tid * ch, v1 = min(v0 + ch, V);
  int cnt = 0;
  for (int v = v0; v < v1; ++v) {
    unsigned mk = __float_as_uint(cpf[(size_t)v * 8 + 7]);
    if (mk & clsbit) cnt++;
  }
  int inc = cnt;
  #pragma unroll
  for (int off = 1; off < 64; off <<= 1) {
    int o = __shfl_up(inc, off);
    if (lane >= off) inc += o;
  }
  if (lane == 63) s_wcnt[wid] = inc;
  __syncthreads();
  int woff = 0;
  for (int k = 0; k < wid; ++k) woff += s_wcnt[k];
  int pcnt = 0;
  #pragma unroll
  for (int k = 0; k < NW; ++k) pcnt += s_wcnt[k];
  int pos = woff + inc - cnt;
  // ---- pass 2: fill LDS for passing candidates (stable order) ----
  for (int v = v0; v < v1; ++v) {
    const float4* cp = reinterpret_cast<const float4*>(cpf) + (size_t)v * 2;
    float4 f2 = cp[1];
    unsigned mk = __float_as_uint(f2.w);
    if (mk & clsbit) {
      if (pos < PCAP) {
        float4 f1 = cp[0];
        int n = __float_as_int(f2.x);
        float lg = logits[(size_t)(b * N + n) * C + cls];
        s_s[pos]   = __fmul_rn(f2.y, lg);
        s_box[pos] = f1;
        s_ar[pos]  = f2.z;
        s_n[pos]   = n;
      }
      pos++;
    }
  }
  __syncthreads();

  bool fail0 = (pcnt > PCAP);
  if (!fail0) {
    if (tid < 64) {
      // ---- wave-exclusive scan: named scalars (true registers) ----
#define NMS_DECL(k) float sr##k, qx##k, qy##k, qz##k, qw##k, pa##k;
      NMS_ALL(NMS_DECL)
#define NMS_INIT(k) { int j = lane * VPW + k; bool in = j < pcnt;            \
      float4 q = s_box[in ? j : 0];                                          \
      sr##k = in ? s_s[j] : -INFINITY;                                       \
      qx##k = in ? q.x : 0.f; qy##k = in ? q.y : 0.f;                        \
      qz##k = in ? q.z : 0.f; qw##k = in ? q.w : 0.f;                        \
      pa##k = in ? s_ar[j] : 0.f; }
      NMS_ALL(NMS_INIT)
      // lane max + smallest-slot argmax, built with a descending >= chain
      float lm = -INFINITY; int bk = 0;
#define NMS_IBK(k) { bool g = (sr##k >= lm); lm = g ? sr##k : lm;            \
      bk = g ? k : bk; }
      NMS_REV(NMS_IBK)
      float lastG = -INFINITY;
      int sfail = 0;
      for (int t = 0; t < P; ++t) {
        float gmax = wave_fmax64(lm);
        if (gmax == -INFINITY) { sfail = 1; break; } // exhausted -> fallback
        lastG = gmax;
        unsigned long long bm = __ballot(lm == gmax);
        int lane_w = __ffsll(bm) - 1; // lowest lane = smallest j (lane-major)
        int k_w = rlane_i(bk, lane_w); // winner's slot, ONE readlane
        int j_w = lane_w * VPW + k_w;
        if (lane == 0) s_selj[t] = j_w;
        float4 wbx = s_box[j_w];       // uniform addr -> LDS broadcast read
        float b0 = wbx.x, b1 = wbx.y, b2 = wbx.z, b3 = wbx.w;
        float wa = __fmul_rn(__fsub_rn(b2, b0), __fsub_rn(b3, b1));
        bool lw = (lane == lane_w);
        float nlm = -INFINITY; int nbk = 0;
        // fast decay: native rcp + exp2 (inter==0 -> wgt==1 exactly);
        // descending order keeps nbk = smallest slot among max ties
#define NMS_DEC(k) {                                                         \
        float x1 = fmaxf(b0, qx##k), y1 = fmaxf(b1, qy##k);                  \
        float x2 = fminf(b2, qz##k), y2 = fminf(b3, qw##k);                  \
        float iw = fmaxf(__fsub_rn(x2, x1), 0.f);                            \
        float ih = fmaxf(__fsub_rn(y2, y1), 0.f);                            \
        float inter = __fmul_rn(iw, ih);                                     \
        float den = __fadd_rn(__fsub_rn(__fadd_rn(wa, pa##k), inter), 1e-9f);\
        float iou = __fmul_rn(inter, fast_rcp(den));                         \
        float m2 = __fmul_rn(__fmul_rn(iou, iou), -1.44269504089f);          \
        float wgt = fast_exp2(m2);                                           \
        float ns = __fmul_rn(sr##k, wgt);                                    \
        sr##k = (lw && k_w == k) ? -INFINITY : ns;                           \
        bool g = (sr##k >= nlm);                                             \
        nlm = g ? sr##k : nlm; nbk = g ? k : nbk; }
        NMS_REV(NMS_DEC)
        lm = nlm; bk = nbk;
      }
      if (!sfail && lastG < TAU) sfail = 1; // verification
      if (lane == 0) s_fail = sfail;
    }
    __syncthreads();
    if (!s_fail) {
      // parallel epilogue: gather winner payloads (all picks valid: lastG>=TAU>0)
      if (tid < P) {
        int wj = s_selj[tid];
        oi[tid] = s_n[wj];
        ov[tid] = 1;
        os[tid] = s_s[wj];
        ob[tid] = s_box[wj];
      }
      return; // pruned result verified
    }
  }

  // ------------- fallback: full-V scan, global scores, EXACT math -------------
  __syncthreads();
  float* sg = sfall + (size_t)blk * N;
  for (int v = tid; v < V; v += NMT) {
    const float* c2 = cpf + (size_t)v * 8 + 4;
    int n = __float_as_int(c2[0]);
    sg[v] = __fmul_rn(c2[1], logits[(size_t)(b * N + n) * C + cls]);
  }
  __syncthreads();

  for (int t = 0; t < P; ++t) {
    float bv = -INFINITY; int bi = INT_MAX;
    for (int v = tid; v < V; v += NMT) {
      float sv = sg[v];
      if (sv > bv) { bv = sv; bi = v; }
    }
    #pragma unroll
    for (int off = 32; off; off >>= 1) {
      float ovv = __shfl_down(bv, off); int oii = __shfl_down(bi, off);
      if (ovv > bv || (ovv == bv && oii < bi)) { bv = ovv; bi = oii; }
    }
    if (lane == 0) { s_red[wid] = bv; s_redi[wid] = bi; }
    __syncthreads();
    float wv = -INFINITY; int wi = INT_MAX;
    #pragma unroll
    for (int k = 0; k < NW; ++k) {
      float v = s_red[k]; int i = s_redi[k];
      if (v > wv || (v == wv && i < wi)) { wv = v; wi = i; }
    }
    __syncthreads(); // partials consumed
    if (wi == INT_MAX) {
      if (tid == 0) for (int u = t; u < P; ++u) {
        oi[u] = 0; ov[u] = 0; os[u] = 0.f;
        ob[u] = make_float4(0.f, 0.f, 0.f, 0.f);
      }
      break; // uniform
    }
    int vd = (wv > 0.0f) ? 1 : 0;
    const float* cw = cpf + (size_t)wi * 8;
    if (tid == 0) {
      int n = __float_as_int(cw[4]);
      oi[t] = n; ov[t] = vd;
      os[t] = __fmul_rn(cw[5], logits[(size_t)(b * N + n) * C + cls]);
      ob[t] = make_float4(cw[0], cw[1], cw[2], cw[3]);
    }
    float w0, w1, w2, w3;
    if (vd) { w0 = cw[0]; w1 = cw[1]; w2 = cw[2]; w3 = cw[3]; }
    else    { w0 = w1 = w2 = w3 = 0.f; }
    float wa = __fmul_rn(__fsub_rn(w2, w0), __fsub_rn(w3, w1));
    for (int v = tid; v < V; v += NMT) {
      float sv = (v == wi) ? -INFINITY : sg[v];
      const float* cq = cpf + (size_t)v * 8;
      float x1 = fmaxf(w0, cq[0]), y1 = fmaxf(w1, cq[1]);
      float x2 = fminf(w2, cq[2]), y2 = fminf(w3, cq[3]);
      float iw = fmaxf(__fsub_rn(x2, x1), 0.f);
      float ih = fmaxf(__fsub_rn(y2, y1), 0.f);
      float inter = __fmul_rn(iw, ih);
      float den = __fadd_rn(__fsub_rn(__fadd_rn(wa, cq[6]), inter), 1e-9f);
      float iou = __fdiv_rn(inter, den);
      float wgt = expf(-__fmul_rn(iou, iou));
      sg[v] = __fmul_rn(sv, wgt);
    }
    __syncthreads();
  }
}

// ---------------------------------------------------------------------------
// Kernel 4: stable top-100 of 2000 + output gather. 1 block/image, 256 thr.
// Wave0: 32 named scalar slots per lane; per-lane argmax slot (bk) maintained
// incrementally, so each step is DPP-max + ballot + ONE readlane; only the
// winner lane re-derives its lane max/argmax (single combined 32-chain).
// ---------------------------------------------------------------------------
__global__ __launch_bounds__(256) void k_topk(
    const float* __restrict__ score, const float* __restrict__ logits,
    const float* __restrict__ obox, const int* __restrict__ oidx,
    const int* __restrict__ oval, const float* __restrict__ osc,
    float* __restrict__ out) {
  __shared__ float s_c[TKN];
  __shared__ int   s_fi[TKN];
  __shared__ int   s_selj[P];
  __shared__ float s_sels[P];

  int b = blockIdx.x;
  int tid = threadIdx.x;
  int lane = tid & 63;

  #pragma unroll
  for (int k = 0; k < TKN / 256; ++k) {
    int j = tid + k * 256;
    if (j < NC * P) {
      int vl = oval[(size_t)b * NC * P + j];
      s_fi[j] = oidx[(size_t)b * NC * P + j];
      s_c[j] = vl ? osc[(size_t)b * NC * P + j] : -BIGF;
    } else {
      s_c[j] = -INFINITY;
      s_fi[j] = 0;
    }
  }
  __syncthreads();

  if (tid < 64) {
#define TK_DECL(k) float cv##k;
    TK_ALL(TK_DECL)
#define TK_INIT(k) { cv##k = s_c[lane * TVPW + k]; }
    TK_ALL(TK_INIT)
    float lm = -INFINITY; int bk = 0;
#define TK_IBK(k) { bool g = (cv##k >= lm); lm = g ? cv##k : lm;             \
    bk = g ? k : bk; }
    TK_REV(TK_IBK)
    for (int t = 0; t < P; ++t) {
      float gmax = wave_fmax64(lm);
      unsigned long long bm = __ballot(lm == gmax);
      int lane_w = __ffsll(bm) - 1;
      int k_w = rlane_i(bk, lane_w); // uniform
      if (lane == 0) { s_selj[t] = lane_w * TVPW + k_w; s_sels[t] = gmax; }
      if (lane == lane_w) {
        // clear picked slot, rebuild lane max + smallest-slot argmax
#define TK_REM(k) { cv##k = (k_w == k) ? -INFINITY : cv##k; }
        TK_ALL(TK_REM)
        lm = -INFINITY; bk = 0;
        TK_REV(TK_IBK)
      }
    }
  }
  __syncthreads();

  // logit_out: [B][P][C]
  for (int k = tid; k < P * C; k += 256) {
    int t = k / C, cls = k % C;
    int j = s_selj[t];
    float sv = s_sels[t];
    bool okp = sv > -BIGF * 0.5f;
    float o = 0.f;
    if (okp) {
      int fi = s_fi[j];
      int bn = b * N + fi;
      o = __fmul_rn(score[bn], logits[(size_t)bn * C + cls]);
    }
    out[((size_t)b * P + t) * C + cls] = o;
  }
  // proposal: [B][P][4] from per-pick winner boxes
  for (int k = tid; k < P * 4; k += 256) {
    int t = k / 4, d = k % 4;
    int j = s_selj[t];
    float sv = s_sels[t];
    bool okp = sv > -BIGF * 0.5f;
    float o = 0.f;
    if (okp) o = obox[((size_t)b * NC * P + j) * 4 + d];
    out[(size_t)B * P * C + ((size_t)b * P + t) * 4 + d] = o;
  }
}

// ---------------------------------------------------------------------------
extern "C" void kernel_launch(void* const* d_in, const int* in_sizes, int n_in,
                              void* d_out, int out_size, void* d_ws, size_t ws_size,
                              hipStream_t stream) {
  const float* score   = (const float*)d_in[0]; // (B,N,1)
  const float* logits  = (const float*)d_in[1]; // (B,N,C)
  const float* regress = (const float*)d_in[2]; // (B,N,4)
  const float* anchors = (const float*)d_in[3]; // (N,4)
  float* out = (float*)d_out;

  char* ws = (char*)d_ws;
  float*    cpack = (float*)(ws + OFF_CPACK);
  unsigned* mask  = (unsigned*)(ws + OFF_MASK);
  int*      bcnt  = (int*)(ws + OFF_BCNT);
  int*      vcnt  = (int*)(ws + OFF_VCNT);
  int*      oidx  = (int*)(ws + OFF_OIDX);
  int*      oval  = (int*)(ws + OFF_OVAL);
  float*    osc   = (float*)(ws + OFF_OSC);
  float*    obox  = (float*)(ws + OFF_OBOX);
  float*    sfall = (float*)(ws + OFF_SFALL);

  k_valid<<<dim3(NB, B), 256, 0, stream>>>(score, logits, mask, bcnt);
  k_compact<<<dim3(GB, B), 256, 0, stream>>>(score, regress, anchors, mask,
                                             bcnt, cpack, vcnt);
  k_nms<<<B * NC, NMT, 0, stream>>>(logits, cpack, vcnt, sfall, oidx, oval,
                                    osc, obox);
  k_topk<<<B, 256, 0, stream>>>(score, logits, obox, oidx, oval, osc, out);
}

// Round 2
// 125.096 us; speedup vs baseline: 1.2929x; 1.2711x over previous
//
#include <hip/hip_runtime.h>
#include <climits>
#include <cstdint>

namespace {
constexpr int B = 4, N = 20000, C = 21, P = 100, NC = 20; // NC = C-1
constexpr float THR  = 0.7f;
constexpr float BIGF = 1.0e9f;
constexpr float MAXR = 4.135166556742356f; // |log(16/1000)| rounded to f32
constexpr float TAU  = 0.8f;               // prune threshold (verified post-hoc)
constexpr int PCAP = 512;                  // pruned-list capacity = VPW*64
constexpr int VPW  = 8;                    // slots per lane, nms wave scan
constexpr int NMT  = 512;                  // k_nms block size
constexpr int TKN  = 2048;                 // padded topk candidate count
constexpr int NB   = (N + 255) / 256;      // 79 k_valid blocks per image
constexpr int GPB  = 2;                    // k_valid blocks per compact block
constexpr int GB   = (NB + GPB - 1) / GPB; // 40 compact blocks per image

// ws layout (bytes)
constexpr size_t OFF_CPACK = 0;                                  // B*N*8 f32 packed cand
constexpr size_t OFF_MASK  = OFF_CPACK + (size_t)B * N * 32;     // B*N u32
constexpr size_t OFF_BCNT  = OFF_MASK  + (size_t)B * N * 4;      // B*NB i32 (+pad)
constexpr size_t OFF_VCNT  = OFF_BCNT  + 2048;                   // B i32 (+pad)
constexpr size_t OFF_OIDX  = OFF_VCNT  + 64;                     // B*NC*P i32
constexpr size_t OFF_OVAL  = OFF_OIDX  + (size_t)B * NC * P * 4; // B*NC*P i32
constexpr size_t OFF_OSC   = OFF_OVAL  + (size_t)B * NC * P * 4; // B*NC*P f32 (orig le)
constexpr size_t OFF_OBOX  = OFF_OSC   + (size_t)B * NC * P * 4; // B*NC*P f32x4
constexpr size_t OFF_SFALL = OFF_OBOX  + (size_t)B * NC * P * 16;// B*NC*N f32 fallback
} // namespace

// ---------------------------------------------------------------------------
// DPP wave64 fmax reduce (VALU-only); result broadcast via readlane 63.
// ---------------------------------------------------------------------------
template <int CTRL, int RM>
__device__ __forceinline__ float dpp_fmax(float x) {
  int t = __builtin_amdgcn_update_dpp(__float_as_int(x), __float_as_int(x),
                                      CTRL, RM, 0xF, false);
  return fmaxf(x, __int_as_float(t));
}
__device__ __forceinline__ float wave_fmax64(float x) {
  x = dpp_fmax<0x111, 0xF>(x); // row_shr:1
  x = dpp_fmax<0x112, 0xF>(x); // row_shr:2
  x = dpp_fmax<0x114, 0xF>(x); // row_shr:4
  x = dpp_fmax<0x118, 0xF>(x); // row_shr:8
  x = dpp_fmax<0x142, 0xA>(x); // row_bcast:15 -> rows 1,3
  x = dpp_fmax<0x143, 0xC>(x); // row_bcast:31 -> rows 2,3
  return __int_as_float(__builtin_amdgcn_readlane(__float_as_int(x), 63));
}
__device__ __forceinline__ int rlane_i(int x, int l) {
  return __builtin_amdgcn_readlane(x, l);
}
// fast native ops for the decay weights (selection-only values; exp2(-0)=1
// exactly so non-overlapping candidates stay bit-identical to np)
__device__ __forceinline__ float fast_rcp(float x) {
  return __builtin_amdgcn_rcpf(x);
}
__device__ __forceinline__ float fast_exp2(float x) {
  return __builtin_amdgcn_exp2f(x);
}
// monotonic float<->uint order map (no NaNs present)
__device__ __forceinline__ unsigned fmap(float v) {
  unsigned u = __float_as_uint(v);
  return (u & 0x80000000u) ? ~u : (u | 0x80000000u);
}
__device__ __forceinline__ float funmap(unsigned u) {
  return __uint_as_float((u & 0x80000000u) ? (u ^ 0x80000000u) : ~u);
}

#define NMS_ALL(X) X(0) X(1) X(2) X(3) X(4) X(5) X(6) X(7)
#define NMS_REV(X) X(7) X(6) X(5) X(4) X(3) X(2) X(1) X(0)

// ---------------------------------------------------------------------------
// Kernel 1: per-anchor le/argmax/valid + tau bitmask + per-block valid count.
// ---------------------------------------------------------------------------
__global__ __launch_bounds__(256) void k_valid(
    const float* __restrict__ score, const float* __restrict__ logits,
    unsigned* __restrict__ mask, int* __restrict__ bcnt) {
  __shared__ int ws[4];
  int tid = threadIdx.x;
  int n = blockIdx.x * 256 + tid;
  int b = blockIdx.y;
  unsigned mk = 0;
  if (n < N) {
    int bn = b * N + n;
    float sc = score[bn];
    const float* lg = logits + (size_t)bn * C;
    float le[C];
    float ms = -INFINITY;
    int lab = 0;
    #pragma unroll
    for (int c = 0; c < C; ++c) {
      le[c] = __fmul_rn(sc, lg[c]);
      if (le[c] > ms) { ms = le[c]; lab = c; }  // strict > keeps first max
    }
    if (ms >= THR && lab > 0) {
      mk = 1u << 20;
      #pragma unroll
      for (int c = 1; c < C; ++c)
        if (le[c] >= TAU) mk |= 1u << (c - 1);
    }
    mask[bn] = mk;
  }
  unsigned long long vb = __ballot(mk != 0);
  if ((tid & 63) == 0) ws[tid >> 6] = __popcll(vb);
  __syncthreads();
  if (tid == 0) bcnt[b * NB + blockIdx.x] = ws[0] + ws[1] + ws[2] + ws[3];
}

// ---------------------------------------------------------------------------
// Kernel 2: segmented stable compaction + box decode into packed 32B records
// {x1,y1,x2,y2, n(bits), score, area, mask(bits)}. Grid (GB, B), 256 thr.
// ---------------------------------------------------------------------------
__global__ __launch_bounds__(256) void k_compact(
    const float* __restrict__ score, const float* __restrict__ regress,
    const float* __restrict__ anchors, const unsigned* __restrict__ mask,
    const int* __restrict__ bcnt, float* __restrict__ cpack,
    int* __restrict__ vcnt) {
  __shared__ int s_base[4], s_tot[4], s_scan[4];
  int g = blockIdx.x, b = blockIdx.y;
  int tid = threadIdx.x, lane = tid & 63, wid = tid >> 6;
  int idx0 = g * GPB;
  int bv = (tid < idx0) ? bcnt[b * NB + tid] : 0;
  int tv = (tid < NB) ? bcnt[b * NB + tid] : 0;
  #pragma unroll
  for (int off = 32; off; off >>= 1) {
    bv += __shfl_down(bv, off);
    tv += __shfl_down(tv, off);
  }
  if (lane == 0) { s_base[wid] = bv; s_tot[wid] = tv; }
  __syncthreads();
  int base = s_base[0] + s_base[1] + s_base[2] + s_base[3];
  if (g == 0 && tid == 0) vcnt[b] = s_tot[0] + s_tot[1] + s_tot[2] + s_tot[3];

  int n0 = g * (GPB * 256) + tid * GPB;
  unsigned bits = 0; int cnt = 0;
  #pragma unroll
  for (int j = 0; j < GPB; ++j) {
    int n = n0 + j;
    if (n < N && (mask[b * N + n] & (1u << 20))) { bits |= 1u << j; cnt++; }
  }
  int inc = cnt;
  #pragma unroll
  for (int off = 1; off < 64; off <<= 1) {
    int o = __shfl_up(inc, off);
    if (lane >= off) inc += o;
  }
  if (lane == 63) s_scan[wid] = inc;
  __syncthreads();
  int woff = 0;
  for (int k = 0; k < wid; ++k) woff += s_scan[k];
  int pos = base + woff + inc - cnt;
  #pragma unroll
  for (int j = 0; j < GPB; ++j) {
    if (!((bits >> j) & 1u)) continue;
    int n = n0 + j;
    int bn = b * N + n;
    const float* an = anchors + (size_t)n * 4;
    float ax1 = an[0], ay1 = an[1], ax2 = an[2], ay2 = an[3];
    float aw = __fsub_rn(ax2, ax1), ah = __fsub_rn(ay2, ay1);
    float acx = __fadd_rn(ax1, __fmul_rn(0.5f, aw));
    float acy = __fadd_rn(ay1, __fmul_rn(0.5f, ah));
    const float* rg = regress + (size_t)bn * 4;
    float dx = rg[0], dy = rg[1];
    float dw = fminf(fmaxf(rg[2], -MAXR), MAXR);
    float dh = fminf(fmaxf(rg[3], -MAXR), MAXR);
    float cx = __fadd_rn(acx, __fmul_rn(dx, aw));
    float cy = __fadd_rn(acy, __fmul_rn(dy, ah));
    float w = __fmul_rn(aw, expf(dw));
    float h = __fmul_rn(ah, expf(dh));
    float hw = __fmul_rn(0.5f, w), hh = __fmul_rn(0.5f, h);
    float x1 = fminf(fmaxf(__fsub_rn(cx, hw), 0.f), 1.f);
    float y1 = fminf(fmaxf(__fsub_rn(cy, hh), 0.f), 1.f);
    float x2 = fminf(fmaxf(__fadd_rn(cx, hw), 0.f), 1.f);
    float y2 = fminf(fmaxf(__fadd_rn(cy, hh), 0.f), 1.f);
    float area = __fmul_rn(__fsub_rn(x2, x1), __fsub_rn(y2, y1));
    unsigned mk = mask[bn];
    float4* cp = reinterpret_cast<float4*>(cpack) + ((size_t)b * N + pos) * 2;
    cp[0] = make_float4(x1, y1, x2, y2);
    cp[1] = make_float4(__int_as_float(n), score[bn], area, __uint_as_float(mk));
    pos++;
  }
}

// ---------------------------------------------------------------------------
// Kernel 3: soft-NMS. One block per (image,class), 512 threads.
// Pruned list (cap PCAP) in LDS; wave0 runs the 100-step scan with named
// scalar state. Per-step serial section minimized: per-lane argmax slot (bk)
// is maintained incrementally inside the decay pass, so winner discovery is
// DPP-max + ballot + ONE readlane; the winner box is fetched with a single
// broadcast ds_read_b128 from LDS (no select chains, no box readlanes).
// Verified by v_99 >= TAU (which also implies every pick is valid, so the
// fast path emits ov=1 unconditionally); any failure -> full-V exact fallback.
// ---------------------------------------------------------------------------
__global__ __launch_bounds__(NMT) void k_nms(
    const float* __restrict__ logits, const float* __restrict__ cpack,
    const int* __restrict__ vcnt, float* __restrict__ sfall,
    int* __restrict__ oidx, int* __restrict__ oval,
    float* __restrict__ osc, float* __restrict__ obox) {
  __shared__ float4 s_box[PCAP];
  __shared__ float  s_ar[PCAP], s_s[PCAP];
  __shared__ int    s_n[PCAP];
  __shared__ int    s_selj[P];
  __shared__ int    s_wcnt[NMT / 64];
  __shared__ int    s_fail;
  __shared__ float  s_red[NMT / 64];
  __shared__ int    s_redi[NMT / 64];

  int blk = blockIdx.x;  // 0..B*NC-1
  int b = blk / NC;
  int cls = blk % NC + 1;
  int V = vcnt[b];
  int tid = threadIdx.x;
  int lane = tid & 63, wid = tid >> 6;
  constexpr int NW = NMT / 64;
  const float* cpf = cpack + (size_t)b * N * 8;
  int* oi = oidx + (size_t)blk * P;
  int* ov = oval + (size_t)blk * P;
  float* os = osc + (size_t)blk * P;
  float4* ob = reinterpret_cast<float4*>(obox) + (size_t)blk * P;
  unsigned clsbit = 1u << (cls - 1);

  // ---- pass 1: count candidates with le >= TAU for this class ----
  int ch = (V + NMT - 1) / NMT;
  int v0 = tid * ch, v1 = min(v0 + ch, V);
  int cnt = 0;
  for (int v = v0; v < v1; ++v) {
    unsigned mk = __float_as_uint(cpf[(size_t)v * 8 + 7]);
    if (mk & clsbit) cnt++;
  }
  int inc = cnt;
  #pragma unroll
  for (int off = 1; off < 64; off <<= 1) {
    int o = __shfl_up(inc, off);
    if (lane >= off) inc += o;
  }
  if (lane == 63) s_wcnt[wid] = inc;
  __syncthreads();
  int woff = 0;
  for (int k = 0; k < wid; ++k) woff += s_wcnt[k];
  int pcnt = 0;
  #pragma unroll
  for (int k = 0; k < NW; ++k) pcnt += s_wcnt[k];
  int pos = woff + inc - cnt;
  // ---- pass 2: fill LDS for passing candidates (stable order) ----
  for (int v = v0; v < v1; ++v) {
    const float4* cp = reinterpret_cast<const float4*>(cpf) + (size_t)v * 2;
    float4 f2 = cp[1];
    unsigned mk = __float_as_uint(f2.w);
    if (mk & clsbit) {
      if (pos < PCAP) {
        float4 f1 = cp[0];
        int n = __float_as_int(f2.x);
        float lg = logits[(size_t)(b * N + n) * C + cls];
        s_s[pos]   = __fmul_rn(f2.y, lg);
        s_box[pos] = f1;
        s_ar[pos]  = f2.z;
        s_n[pos]   = n;
      }
      pos++;
    }
  }
  __syncthreads();

  bool fail0 = (pcnt > PCAP);
  if (!fail0) {
    if (tid < 64) {
      // ---- wave-exclusive scan: named scalars (true registers) ----
#define NMS_DECL(k) float sr##k, qx##k, qy##k, qz##k, qw##k, pa##k;
      NMS_ALL(NMS_DECL)
#define NMS_INIT(k) { int j = lane * VPW + k; bool in = j < pcnt;            \
      float4 q = s_box[in ? j : 0];                                          \
      sr##k = in ? s_s[j] : -INFINITY;                                       \
      qx##k = in ? q.x : 0.f; qy##k = in ? q.y : 0.f;                        \
      qz##k = in ? q.z : 0.f; qw##k = in ? q.w : 0.f;                        \
      pa##k = in ? s_ar[j] : 0.f; }
      NMS_ALL(NMS_INIT)
      // lane max + smallest-slot argmax, built with a descending >= chain
      float lm = -INFINITY; int bk = 0;
#define NMS_IBK(k) { bool g = (sr##k >= lm); lm = g ? sr##k : lm;            \
      bk = g ? k : bk; }
      NMS_REV(NMS_IBK)
      float lastG = -INFINITY;
      int sfail = 0;
      for (int t = 0; t < P; ++t) {
        float gmax = wave_fmax64(lm);
        if (gmax == -INFINITY) { sfail = 1; break; } // exhausted -> fallback
        lastG = gmax;
        unsigned long long bm = __ballot(lm == gmax);
        int lane_w = __ffsll(bm) - 1; // lowest lane = smallest j (lane-major)
        int k_w = rlane_i(bk, lane_w); // winner's slot, ONE readlane
        int j_w = lane_w * VPW + k_w;
        if (lane == 0) s_selj[t] = j_w;
        float4 wbx = s_box[j_w];       // uniform addr -> LDS broadcast read
        float b0 = wbx.x, b1 = wbx.y, b2 = wbx.z, b3 = wbx.w;
        float wa = __fmul_rn(__fsub_rn(b2, b0), __fsub_rn(b3, b1));
        bool lw = (lane == lane_w);
        float nlm = -INFINITY; int nbk = 0;
        // fast decay: native rcp + exp2 (inter==0 -> wgt==1 exactly);
        // descending order keeps nbk = smallest slot among max ties
#define NMS_DEC(k) {                                                         \
        float x1 = fmaxf(b0, qx##k), y1 = fmaxf(b1, qy##k);                  \
        float x2 = fminf(b2, qz##k), y2 = fminf(b3, qw##k);                  \
        float iw = fmaxf(__fsub_rn(x2, x1), 0.f);                            \
        float ih = fmaxf(__fsub_rn(y2, y1), 0.f);                            \
        float inter = __fmul_rn(iw, ih);                                     \
        float den = __fadd_rn(__fsub_rn(__fadd_rn(wa, pa##k), inter), 1e-9f);\
        float iou = __fmul_rn(inter, fast_rcp(den));                         \
        float m2 = __fmul_rn(__fmul_rn(iou, iou), -1.44269504089f);          \
        float wgt = fast_exp2(m2);                                           \
        float ns = __fmul_rn(sr##k, wgt);                                    \
        sr##k = (lw && k_w == k) ? -INFINITY : ns;                           \
        bool g = (sr##k >= nlm);                                             \
        nlm = g ? sr##k : nlm; nbk = g ? k : nbk; }
        NMS_REV(NMS_DEC)
        lm = nlm; bk = nbk;
      }
      if (!sfail && lastG < TAU) sfail = 1; // verification
      if (lane == 0) s_fail = sfail;
    }
    __syncthreads();
    if (!s_fail) {
      // parallel epilogue: gather winner payloads (all picks valid: lastG>=TAU>0)
      if (tid < P) {
        int wj = s_selj[tid];
        oi[tid] = s_n[wj];
        ov[tid] = 1;
        os[tid] = s_s[wj];
        ob[tid] = s_box[wj];
      }
      return; // pruned result verified
    }
  }

  // ------------- fallback: full-V scan, global scores, EXACT math -------------
  __syncthreads();
  float* sg = sfall + (size_t)blk * N;
  for (int v = tid; v < V; v += NMT) {
    const float* c2 = cpf + (size_t)v * 8 + 4;
    int n = __float_as_int(c2[0]);
    sg[v] = __fmul_rn(c2[1], logits[(size_t)(b * N + n) * C + cls]);
  }
  __syncthreads();

  for (int t = 0; t < P; ++t) {
    float bv = -INFINITY; int bi = INT_MAX;
    for (int v = tid; v < V; v += NMT) {
      float sv = sg[v];
      if (sv > bv) { bv = sv; bi = v; }
    }
    #pragma unroll
    for (int off = 32; off; off >>= 1) {
      float ovv = __shfl_down(bv, off); int oii = __shfl_down(bi, off);
      if (ovv > bv || (ovv == bv && oii < bi)) { bv = ovv; bi = oii; }
    }
    if (lane == 0) { s_red[wid] = bv; s_redi[wid] = bi; }
    __syncthreads();
    float wv = -INFINITY; int wi = INT_MAX;
    #pragma unroll
    for (int k = 0; k < NW; ++k) {
      float v = s_red[k]; int i = s_redi[k];
      if (v > wv || (v == wv && i < wi)) { wv = v; wi = i; }
    }
    __syncthreads(); // partials consumed
    if (wi == INT_MAX) {
      if (tid == 0) for (int u = t; u < P; ++u) {
        oi[u] = 0; ov[u] = 0; os[u] = 0.f;
        ob[u] = make_float4(0.f, 0.f, 0.f, 0.f);
      }
      break; // uniform
    }
    int vd = (wv > 0.0f) ? 1 : 0;
    const float* cw = cpf + (size_t)wi * 8;
    if (tid == 0) {
      int n = __float_as_int(cw[4]);
      oi[t] = n; ov[t] = vd;
      os[t] = __fmul_rn(cw[5], logits[(size_t)(b * N + n) * C + cls]);
      ob[t] = make_float4(cw[0], cw[1], cw[2], cw[3]);
    }
    float w0, w1, w2, w3;
    if (vd) { w0 = cw[0]; w1 = cw[1]; w2 = cw[2]; w3 = cw[3]; }
    else    { w0 = w1 = w2 = w3 = 0.f; }
    float wa = __fmul_rn(__fsub_rn(w2, w0), __fsub_rn(w3, w1));
    for (int v = tid; v < V; v += NMT) {
      float sv = (v == wi) ? -INFINITY : sg[v];
      const float* cq = cpf + (size_t)v * 8;
      float x1 = fmaxf(w0, cq[0]), y1 = fmaxf(w1, cq[1]);
      float x2 = fminf(w2, cq[2]), y2 = fminf(w3, cq[3]);
      float iw = fmaxf(__fsub_rn(x2, x1), 0.f);
      float ih = fmaxf(__fsub_rn(y2, y1), 0.f);
      float inter = __fmul_rn(iw, ih);
      float den = __fadd_rn(__fsub_rn(__fadd_rn(wa, cq[6]), inter), 1e-9f);
      float iou = __fdiv_rn(inter, den);
      float wgt = expf(-__fmul_rn(iou, iou));
      sg[v] = __fmul_rn(sv, wgt);
    }
    __syncthreads();
  }
}

// ---------------------------------------------------------------------------
// Kernel 4: stable top-100 via full bitonic sort of 2048 packed 64-bit keys.
// key = (monotonic-mapped value bits << 32) | ~index  -> descending key order
// is exactly lax.top_k's stable order (value desc, smallest index on ties).
// Keys are unique (index embedded), so the sort yields a strict total order.
// 1 block/image, 256 threads; 66 barriered compare-exchange stages replace
// the former 100-step single-wave serial argmax scan (latency-bound).
// ---------------------------------------------------------------------------
__global__ __launch_bounds__(256) void k_topk(
    const float* __restrict__ score, const float* __restrict__ logits,
    const float* __restrict__ obox, const int* __restrict__ oidx,
    const int* __restrict__ oval, const float* __restrict__ osc,
    float* __restrict__ out) {
  __shared__ unsigned long long s_key[TKN];
  __shared__ int s_fi[TKN];

  int b = blockIdx.x;
  int tid = threadIdx.x;
  size_t base = (size_t)b * NC * P;

  // build keys (pads sort after everything real: -INF < -BIGF)
  #pragma unroll
  for (int q = 0; q < TKN / 256; ++q) {
    int j = tid + q * 256;
    unsigned hi;
    if (j < NC * P) {
      int vl = oval[base + j];
      float c = vl ? osc[base + j] : -BIGF;
      s_fi[j] = oidx[base + j];
      hi = fmap(c);
    } else {
      s_fi[j] = 0;
      hi = fmap(-INFINITY);
    }
    s_key[j] = ((unsigned long long)hi << 32) | (unsigned)(~j);
  }

  // bitonic sort, descending
  for (int k = 2; k <= TKN; k <<= 1) {
    for (int j = k >> 1; j > 0; j >>= 1) {
      __syncthreads();
      #pragma unroll
      for (int q = 0; q < TKN / 2 / 256; ++q) {
        int p = tid + q * 256;
        int i = ((p & ~(j - 1)) << 1) | (p & (j - 1));
        int l = i | j;
        unsigned long long a = s_key[i], bb = s_key[l];
        bool desc = ((i & k) == 0);
        if (desc ? (a < bb) : (a > bb)) { s_key[i] = bb; s_key[l] = a; }
      }
    }
  }
  __syncthreads();

  // logit_out: [B][P][C]
  for (int kk = tid; kk < P * C; kk += 256) {
    int t = kk / C, cls = kk % C;
    unsigned long long kt = s_key[t];
    float sv = funmap((unsigned)(kt >> 32));
    int j = (int)(~(unsigned)kt);
    bool okp = sv > -BIGF * 0.5f;
    float o = 0.f;
    if (okp) {
      int fi = s_fi[j];
      int bn = b * N + fi;
      o = __fmul_rn(score[bn], logits[(size_t)bn * C + cls]);
    }
    out[((size_t)b * P + t) * C + cls] = o;
  }
  // proposal: [B][P][4] from per-pick winner boxes
  for (int kk = tid; kk < P * 4; kk += 256) {
    int t = kk / 4, d = kk % 4;
    unsigned long long kt = s_key[t];
    float sv = funmap((unsigned)(kt >> 32));
    int j = (int)(~(unsigned)kt);
    bool okp = sv > -BIGF * 0.5f;
    float o = 0.f;
    if (okp) o = obox[(base + j) * 4 + d];
    out[(size_t)B * P * C + ((size_t)b * P + t) * 4 + d] = o;
  }
}

// ---------------------------------------------------------------------------
extern "C" void kernel_launch(void* const* d_in, const int* in_sizes, int n_in,
                              void* d_out, int out_size, void* d_ws, size_t ws_size,
                              hipStream_t stream) {
  const float* score   = (const float*)d_in[0]; // (B,N,1)
  const float* logits  = (const float*)d_in[1]; // (B,N,C)
  const float* regress = (const float*)d_in[2]; // (B,N,4)
  const float* anchors = (const float*)d_in[3]; // (N,4)
  float* out = (float*)d_out;

  char* ws = (char*)d_ws;
  float*    cpack = (float*)(ws + OFF_CPACK);
  unsigned* mask  = (unsigned*)(ws + OFF_MASK);
  int*      bcnt  = (int*)(ws + OFF_BCNT);
  int*      vcnt  = (int*)(ws + OFF_VCNT);
  int*      oidx  = (int*)(ws + OFF_OIDX);
  int*      oval  = (int*)(ws + OFF_OVAL);
  float*    osc   = (float*)(ws + OFF_OSC);
  float*    obox  = (float*)(ws + OFF_OBOX);
  float*    sfall = (float*)(ws + OFF_SFALL);

  k_valid<<<dim3(NB, B), 256, 0, stream>>>(score, logits, mask, bcnt);
  k_compact<<<dim3(GB, B), 256, 0, stream>>>(score, regress, anchors, mask,
                                             bcnt, cpack, vcnt);
  k_nms<<<B * NC, NMT, 0, stream>>>(logits, cpack, vcnt, sfall, oidx, oval,
                                    osc, obox);
  k_topk<<<B, 256, 0, stream>>>(score, logits, obox, oidx, oval, osc, out);
}